// Round 12
// baseline (388.884 us; speedup 1.0000x reference)
//
#include <hip/hip_runtime.h>
#include <stdint.h>

typedef unsigned short u16;
typedef unsigned int   u32;
typedef __attribute__((ext_vector_type(8))) __bf16 bf16x8;
typedef __attribute__((ext_vector_type(4))) float  f32x4;
typedef __attribute__((ext_vector_type(4))) short  s16x4;

#define NB  64
#define NQ  784
#define NK  196
#define NKP 208      // nk padded to 13*16
#define DM  512

static __device__ inline u16 f2bf(float f) {
  u32 u = __float_as_uint(f);
  u32 r = (u + 0x7fffu + ((u >> 16) & 1u)) >> 16;
  return (u16)r;
}

static __device__ inline bf16x8 ld8(const u16* p) {
  return *reinterpret_cast<const bf16x8*>(p);
}
static __device__ inline f32x4 mfma16(bf16x8 a, bf16x8 b, f32x4 c) {
  return __builtin_amdgcn_mfma_f32_16x16x32_bf16(a, b, c, 0, 0, 0);
}
// K=16 bf16 MFMA (4 bf16 per lane per operand)
static __device__ inline f32x4 mfma16k16(s16x4 a, s16x4 b, f32x4 c) {
#if __has_builtin(__builtin_amdgcn_mfma_f32_16x16x16bf16_1k)
  return __builtin_amdgcn_mfma_f32_16x16x16bf16_1k(a, b, c, 0, 0, 0);
#elif __has_builtin(__builtin_amdgcn_mfma_f32_16x16x16_bf16)
  typedef __attribute__((ext_vector_type(4))) __bf16 bf16x4_t;
  union { s16x4 s; bf16x4_t b; } ua, ub;
  ua.s = a; ub.s = b;
  return __builtin_amdgcn_mfma_f32_16x16x16_bf16(ua.b, ub.b, c, 0, 0, 0);
#else
  asm volatile("v_mfma_f32_16x16x16_bf16 %0, %1, %2, %0\n\ts_nop 7\n\ts_nop 7"
               : "+v"(c) : "v"(a), "v"(b));
  return c;
#endif
}

// wave-uniform float -> SGPR
static __device__ inline float sgpr_f(float x) {
  return __uint_as_float(__builtin_amdgcn_readfirstlane(__float_as_uint(x)));
}

// async global -> LDS, 16B per lane; LDS dest must be wave-uniform base
static __device__ inline void gl_lds16(const void* g, void* l) {
  __builtin_amdgcn_global_load_lds(
      (const __attribute__((address_space(1))) void*)g,
      (__attribute__((address_space(3))) void*)l, 16, 0, 0);
}

// ---------------- fp32 -> bf16 conversion ----------------
__global__ __launch_bounds__(256) void cvt_kernel(const float* __restrict__ in,
                                                  u16* __restrict__ out, int n) {
  int i = (blockIdx.x * 256 + threadIdx.x) * 4;
  if (i + 3 < n) {
    float4 f = *reinterpret_cast<const float4*>(in + i);
    ushort4 o;
    o.x = f2bf(f.x); o.y = f2bf(f.y); o.z = f2bf(f.z); o.w = f2bf(f.w);
    *reinterpret_cast<ushort4*>(out + i) = o;
  }
}

// ---------------- spatial-reduce + LayerNorm -> bf16 x_ln [64][208][512] ----------------
__global__ __launch_bounds__(256) void ln_kernel(const float* __restrict__ q,
                                                 const float* __restrict__ sr_w,
                                                 const float* __restrict__ sr_b,
                                                 const float* __restrict__ ln_w,
                                                 const float* __restrict__ ln_b,
                                                 u16* __restrict__ xln) {
  int wave = blockIdx.x * 4 + (threadIdx.x >> 6);
  int lane = threadIdx.x & 63;
  if (wave >= NB * NKP) return;
  int b = wave / NKP, n = wave % NKP;
  u16* outp = xln + ((size_t)(b * NKP + n)) * DM;
  if (n >= NK) {  // zero pad row
    *reinterpret_cast<uint4*>(outp + lane * 8) = make_uint4(0u, 0u, 0u, 0u);
    return;
  }
  int src_n = (2 * (n / 14)) * 28 + 2 * (n % 14);
  const float* row = q + ((size_t)(b * NQ + src_n)) * DM;
  int c0 = lane * 4, c1 = 256 + lane * 4;
  float4 x0 = *reinterpret_cast<const float4*>(row + c0);
  float4 x1 = *reinterpret_cast<const float4*>(row + c1);
  float4 w0 = *reinterpret_cast<const float4*>(sr_w + c0);
  float4 w1 = *reinterpret_cast<const float4*>(sr_w + c1);
  float4 s0 = *reinterpret_cast<const float4*>(sr_b + c0);
  float4 s1 = *reinterpret_cast<const float4*>(sr_b + c1);
  float y[8];
  y[0] = x0.x * w0.x + s0.x; y[1] = x0.y * w0.y + s0.y;
  y[2] = x0.z * w0.z + s0.z; y[3] = x0.w * w0.w + s0.w;
  y[4] = x1.x * w1.x + s1.x; y[5] = x1.y * w1.y + s1.y;
  y[6] = x1.z * w1.z + s1.z; y[7] = x1.w * w1.w + s1.w;
  float s = 0.f, ss = 0.f;
  #pragma unroll
  for (int i = 0; i < 8; i++) { s += y[i]; ss += y[i] * y[i]; }
  #pragma unroll
  for (int off = 1; off < 64; off <<= 1) {
    s += __shfl_xor(s, off); ss += __shfl_xor(ss, off);
  }
  float mu = s * (1.f / 512.f);
  float var = ss * (1.f / 512.f) - mu * mu;
  float rs = rsqrtf(var + 1e-5f);
  float4 lw0 = *reinterpret_cast<const float4*>(ln_w + c0);
  float4 lw1 = *reinterpret_cast<const float4*>(ln_w + c1);
  float4 lb0 = *reinterpret_cast<const float4*>(ln_b + c0);
  float4 lb1 = *reinterpret_cast<const float4*>(ln_b + c1);
  ushort4 o0, o1;
  o0.x = f2bf((y[0] - mu) * rs * lw0.x + lb0.x);
  o0.y = f2bf((y[1] - mu) * rs * lw0.y + lb0.y);
  o0.z = f2bf((y[2] - mu) * rs * lw0.z + lb0.z);
  o0.w = f2bf((y[3] - mu) * rs * lw0.w + lb0.w);
  o1.x = f2bf((y[4] - mu) * rs * lw1.x + lb1.x);
  o1.y = f2bf((y[5] - mu) * rs * lw1.y + lb1.y);
  o1.z = f2bf((y[6] - mu) * rs * lw1.z + lb1.z);
  o1.w = f2bf((y[7] - mu) * rs * lw1.w + lb1.w);
  *reinterpret_cast<ushort4*>(outp + c0) = o0;
  *reinterpret_cast<ushort4*>(outp + c1) = o1;
}

// ---------------- shared GEMM body: C[M,512] = A[M,512]*W[512,512]^T + bias ------------
// 128x128 tile, 4 waves (2x2) of 64x64, BK=32, global_load_lds staging, dbuf.
// OMODE: 0 = bf16 C [row][col], 1 = fp32 C [row][col],
//        2 = bf16 V tiled: C[b][kt][col(d)][k%16]
template <int OMODE>
static __device__ __forceinline__ void gemm_body(const u16* __restrict__ A,
                                                 const u16* __restrict__ Bw,
                                                 const float* __restrict__ bias,
                                                 void* __restrict__ Cptr,
                                                 int nt, int mt,
                                                 u16* Al0, u16* Al1,
                                                 u16* Bl0, u16* Bl1) {
  int wv = threadIdx.x >> 6, lane = threadIdx.x & 63;
  int lr = lane & 15, lg = lane >> 4;
  int wr = wv >> 1, wc = wv & 1;
  int row0 = mt * 128, col0 = nt * 128;

  auto stage = [&](int kk, int bi) {
    u16* Al = bi ? Al1 : Al0;
    u16* Bl = bi ? Bl1 : Bl0;
    #pragma unroll
    for (int i = 0; i < 4; i++) {
      int t = wv * 4 + i;                    // 0..15
      int rr = (t & 7) * 16 + (lane >> 2);
      int cc = lane & 3;
      if (t < 8) {
        gl_lds16(A + (size_t)(row0 + rr) * DM + kk + cc * 8, (char*)Al + t * 1024);
      } else {
        gl_lds16(Bw + (size_t)(col0 + rr) * DM + kk + cc * 8, (char*)Bl + (t - 8) * 1024);
      }
    }
  };

  f32x4 acc[4][4] = {};
  stage(0, 0);
  __syncthreads();
  for (int s = 0; s < 16; s++) {
    int bi = s & 1;
    if (s < 15) stage((s + 1) * 32, bi ^ 1);
    u16* Al = bi ? Al1 : Al0;
    u16* Bl = bi ? Bl1 : Bl0;
    bf16x8 am[4], bn[4];
    #pragma unroll
    for (int m = 0; m < 4; m++)
      am[m] = ld8(Al + (wr * 64 + m * 16 + lr) * 32 + lg * 8);
    #pragma unroll
    for (int n = 0; n < 4; n++)
      bn[n] = ld8(Bl + (wc * 64 + n * 16 + lr) * 32 + lg * 8);
    #pragma unroll
    for (int m = 0; m < 4; m++)
      #pragma unroll
      for (int n = 0; n < 4; n++)
        acc[m][n] = mfma16(am[m], bn[n], acc[m][n]);
    __syncthreads();
  }
  if (OMODE == 2) {
    #pragma unroll
    for (int n = 0; n < 4; n++) {
      int col = col0 + wc * 64 + n * 16 + lr;
      float bs = bias[col];
      #pragma unroll
      for (int m = 0; m < 4; m++) {
        int rbase = row0 + wr * 64 + m * 16 + lg * 4;
        int bb = rbase / NKP;
        int kr = rbase % NKP;          // kr&15 == lg*4
        ushort4 o4;
        o4.x = f2bf(acc[m][n][0] + bs);
        o4.y = f2bf(acc[m][n][1] + bs);
        o4.z = f2bf(acc[m][n][2] + bs);
        o4.w = f2bf(acc[m][n][3] + bs);
        size_t dst = (((size_t)bb * 13 + (kr >> 4)) * 512 + col) * 16 + (kr & 15);
        *reinterpret_cast<ushort4*>(&((u16*)Cptr)[dst]) = o4;
      }
    }
  } else {
    #pragma unroll
    for (int n = 0; n < 4; n++) {
      int col = col0 + wc * 64 + n * 16 + lr;
      float bs = bias[col];
      #pragma unroll
      for (int m = 0; m < 4; m++) {
        #pragma unroll
        for (int r = 0; r < 4; r++) {
          int row = row0 + wr * 64 + m * 16 + lg * 4 + r;
          float v = acc[m][n][r] + bs;
          if (OMODE == 0) {
            ((u16*)Cptr)[(size_t)row * DM + col] = f2bf(v);
          } else {
            ((float*)Cptr)[(size_t)row * DM + col] = v;
          }
        }
      }
    }
  }
}

template <int OMODE>
__global__ __launch_bounds__(256) void gemm2_kernel(const u16* __restrict__ A,
                                                    const u16* __restrict__ Bw,
                                                    const float* __restrict__ bias,
                                                    void* __restrict__ Cptr) {
  __shared__ __align__(16) u16 Al[2][128 * 32];
  __shared__ __align__(16) u16 Bl[2][128 * 32];
  gemm_body<OMODE>(A, Bw, bias, Cptr, blockIdx.x, blockIdx.y,
                   &Al[0][0], &Al[1][0], &Bl[0][0], &Bl[1][0]);
}

// fused K-proj (OMODE 0) + V-proj (OMODE 2): blockIdx.z selects.
__global__ __launch_bounds__(256) void kvgemm_kernel(const u16* __restrict__ A,
                                                     const u16* __restrict__ Wk,
                                                     const float* __restrict__ bk,
                                                     void* __restrict__ Kout,
                                                     const u16* __restrict__ Wv,
                                                     const float* __restrict__ bv,
                                                     void* __restrict__ Vout) {
  __shared__ __align__(16) u16 Al[2][128 * 32];
  __shared__ __align__(16) u16 Bl[2][128 * 32];
  if (blockIdx.z == 0) {
    gemm_body<0>(A, Wk, bk, Kout, blockIdx.x, blockIdx.y,
                 &Al[0][0], &Al[1][0], &Bl[0][0], &Bl[1][0]);
  } else {
    gemm_body<2>(A, Wv, bv, Vout, blockIdx.x, blockIdx.y,
                 &Al[0][0], &Al[1][0], &Bl[0][0], &Bl[1][0]);
  }
}

// ---------------- fused attn: K-only LDS (32KB), Q from L1, XCD-clustered --------------
// Round-12 change: Ql removed entirely. The 16KB Q tile is re-read 13x -> it
// lives in L1 (32KB/CU); fragments load directly from global per kt. LDS drops
// 48->32KB: 5 blocks/CU by LDS, VGPR ~100 -> ~20 waves/CU (3x round-11
// residency). Diagnosis: 7 rounds flat at ~205us with every pipe <=29% busy =
// wave starvation, while gemm2 (same skeleton, 5+ blocks/CU) runs at ~900TF.
__global__ __launch_bounds__(256) void attn_kernel(const u16* __restrict__ Q,
                                                   const u16* __restrict__ K,
                                                   const u16* __restrict__ VTt,
                                                   const float* __restrict__ tw,
                                                   u16* __restrict__ Oat) {
  __shared__ __align__(16) u16 Kl[2][16 * 512];   // 2 x 16KB, chunk-major
  int i = blockIdx.x;
  int g8 = i & 7;            // XCD group == b%8
  int j = i >> 3;            // 0..391
  int qt = j % 49;
  int b = g8 + 8 * (j / 49);
  int tid = threadIdx.x, wv = tid >> 6, lane = tid & 63;
  int lr = lane & 15, lg = lane >> 4;
  int q0 = qt * 16, g0 = wv * 2;

  const u16* Qb = Q + ((size_t)(b * NQ + q0)) * DM;
  const u16* Kb = K + (size_t)b * NKP * DM;
  const u16* Vtb = VTt + (size_t)b * 13 * 8192;

  // wave-uniform mixing weights -> SGPRs (1/sqrt(64) folded)
  float w0[8], w1[8];
  #pragma unroll
  for (int h = 0; h < 8; h++) {
    w0[h] = sgpr_f(tw[(g0 + 0) * 8 + h] * 0.125f);
    w1[h] = sgpr_f(tw[(g0 + 1) * 8 + h] * 0.125f);
  }

  // chunk-major staging: slot s = g*64+lane -> (c = g*4 + lane>>4, r = lane&15)
  auto stageK = [&](int kt, int bi) {
    #pragma unroll
    for (int i2 = 0; i2 < 4; i2++) {
      int g = wv * 4 + i2;
      gl_lds16(Kb + (size_t)(kt * 16 + (lane & 15)) * DM + (g * 4 + (lane >> 4)) * 8,
               (char*)&Kl[bi][0] + g * 1024);
    }
  };
  stageK(0, 0);
  __syncthreads();

  // per-lane Q row pointer (L1-resident after kt=0)
  const u16* qrow = Qb + (size_t)lr * DM;

  f32x4 o[2][4] = {};
  float sum0 = 0.f, sum1 = 0.f;

  for (int kt = 0; kt < 13; kt++) {
    int bi = kt & 1;
    if (kt < 12) stageK(kt + 1, bi ^ 1);
    const u16* kbase = &Kl[bi][0] + lg * 128 + lr * 8;

    // QK^T (swapped): lane holds q = lr, k = kt*16 + lg*4 + r.
    // K fragments: LDS base + compile-time imm. Q fragments: global (L1-hit).
    f32x4 sa = {0.f, 0.f, 0.f, 0.f};
    f32x4 sb = {0.f, 0.f, 0.f, 0.f};
    #pragma unroll
    for (int h = 0; h < 8; h++) {
      bf16x8 kf0 = ld8(kbase + h * 1024);
      bf16x8 kf1 = ld8(kbase + h * 1024 + 512);
      bf16x8 qf0 = ld8(qrow + h * 64 + lg * 8);
      bf16x8 qf1 = ld8(qrow + h * 64 + 32 + lg * 8);
      f32x4 t4 = {0.f, 0.f, 0.f, 0.f};
      t4 = mfma16(kf0, qf0, t4);
      t4 = mfma16(kf1, qf1, t4);
      sa += t4 * w0[h];
      sb += t4 * w1[h];
    }
    bool masked = (kt == 12) && (lg != 0);   // k >= 196
    float a0 = masked ? 0.f : __expf(sa[0]);
    float a1 = masked ? 0.f : __expf(sa[1]);
    float a2 = masked ? 0.f : __expf(sa[2]);
    float a3 = masked ? 0.f : __expf(sa[3]);
    float b0 = masked ? 0.f : __expf(sb[0]);
    float b1 = masked ? 0.f : __expf(sb[1]);
    float b2 = masked ? 0.f : __expf(sb[2]);
    float b3 = masked ? 0.f : __expf(sb[3]);
    sum0 += (a0 + a1) + (a2 + a3);
    sum1 += (b0 + b1) + (b2 + b3);
    union { __bf16 e[4]; s16x4 sv; } pk;
    pk.e[0] = (__bf16)a0; pk.e[1] = (__bf16)a1;
    pk.e[2] = (__bf16)a2; pk.e[3] = (__bf16)a3;
    s16x4 pa0 = pk.sv;
    pk.e[0] = (__bf16)b0; pk.e[1] = (__bf16)b1;
    pk.e[2] = (__bf16)b2; pk.e[3] = (__bf16)b3;
    s16x4 pa1 = pk.sv;

    // V fragment loads (tiled global, L2-local), just before PV
    s16x4 vb[2][4];
    #pragma unroll
    for (int gi = 0; gi < 2; gi++) {
      #pragma unroll
      for (int j2 = 0; j2 < 4; j2++) {
        int d = (g0 + gi) * 64 + j2 * 16 + lr;
        vb[gi][j2] = *reinterpret_cast<const s16x4*>(
            Vtb + (size_t)kt * 8192 + d * 16 + lg * 4);
      }
    }

    // PV: o += P[kt] x V[kt]
    #pragma unroll
    for (int gi = 0; gi < 2; gi++) {
      s16x4 pa = (gi == 0) ? pa0 : pa1;
      #pragma unroll
      for (int j2 = 0; j2 < 4; j2++)
        o[gi][j2] = mfma16k16(pa, vb[gi][j2], o[gi][j2]);
    }
    __syncthreads();   // stage(kt+1) complete; all waves done with Kl[bi]
  }

  // complete row sums (k split across lane groups 16 apart)
  sum0 += __shfl_xor(sum0, 16); sum0 += __shfl_xor(sum0, 32);
  sum1 += __shfl_xor(sum1, 16); sum1 += __shfl_xor(sum1, 32);
  float inv0 = 1.0f / sum0;    // valid for q = lr
  float inv1 = 1.0f / sum1;
  float iv0[4], iv1[4];
  #pragma unroll
  for (int r = 0; r < 4; r++) {
    iv0[r] = __shfl(inv0, lg * 4 + r);
    iv1[r] = __shfl(inv1, lg * 4 + r);
  }
  #pragma unroll
  for (int gi = 0; gi < 2; gi++) {
    int g = g0 + gi;
    #pragma unroll
    for (int j2 = 0; j2 < 4; j2++) {
      #pragma unroll
      for (int r = 0; r < 4; r++) {
        int q = lg * 4 + r;
        float iv = (gi == 0) ? iv0[r] : iv1[r];
        Oat[((size_t)(b * NQ + q0 + q)) * DM + g * 64 + j2 * 16 + lr] =
            f2bf(o[gi][j2][r] * iv);
      }
    }
  }
}

// ---------------- launch ----------------
extern "C" void kernel_launch(void* const* d_in, const int* in_sizes, int n_in,
                              void* d_out, int out_size, void* d_ws, size_t ws_size,
                              hipStream_t stream) {
  const float* queries = (const float*)d_in[0];
  const float* Wq = (const float*)d_in[3];
  const float* bq = (const float*)d_in[4];
  const float* Wk = (const float*)d_in[5];
  const float* bk = (const float*)d_in[6];
  const float* Wv = (const float*)d_in[7];
  const float* bv = (const float*)d_in[8];
  const float* Wo = (const float*)d_in[9];
  const float* bo = (const float*)d_in[10];
  const float* sr_w = (const float*)d_in[11];
  const float* sr_b = (const float*)d_in[12];
  const float* ln_w = (const float*)d_in[13];
  const float* ln_b = (const float*)d_in[14];
  const float* tw = (const float*)d_in[15];

  char* ws = (char*)d_ws;
  u16* wq_bf = (u16*)(ws + 0);          // 512KB
  u16* wk_bf = (u16*)(ws + 524288);
  u16* wv_bf = (u16*)(ws + 1048576);
  u16* wo_bf = (u16*)(ws + 1572864);
  u16* xln   = (u16*)(ws + 2097152);    // 64*208*512*2 = 13,631,488
  u16* Kbuf  = (u16*)(ws + 15728640);   // 13,631,488
  u16* VTt   = (u16*)(ws + 29360128);   // 64*13*512*16*2 = 13,631,488
  u16* Qbuf  = (u16*)(ws + 42991616);   // 64*784*512*2 = 51,380,224
  u16* qbf   = (u16*)(ws + 94371840);   // 51,380,224 -> end 145,752,064
  u16* Oat   = qbf;                     // qbf dead after Q-proj; attn reuses it
  if (ws_size < 145752064u) return;     // fail loudly (output stays poisoned)

  const int NW = 262144;  // 512*512
  cvt_kernel<<<256, 256, 0, stream>>>(Wq, wq_bf, NW);
  cvt_kernel<<<256, 256, 0, stream>>>(Wk, wk_bf, NW);
  cvt_kernel<<<256, 256, 0, stream>>>(Wv, wv_bf, NW);
  cvt_kernel<<<256, 256, 0, stream>>>(Wo, wo_bf, NW);
  // queries fp32 -> bf16 (25,690,112 elements)
  cvt_kernel<<<25088, 256, 0, stream>>>(queries, qbf, NB * NQ * DM);

  ln_kernel<<<(NB * NKP) / 4, 256, 0, stream>>>(queries, sr_w, sr_b, ln_w, ln_b, xln);

  // Q = qbf @ Wq^T + bq   M = 50176
  gemm2_kernel<0><<<dim3(4, 392), 256, 0, stream>>>(qbf, wq_bf, bq, Qbuf);
  // K-proj + V-proj fused (z=0: K [row][col] bf16; z=1: V tiled)
  kvgemm_kernel<<<dim3(4, 104, 2), 256, 0, stream>>>(xln, wk_bf, bk, Kbuf,
                                                     wv_bf, bv, VTt);

  attn_kernel<<<dim3(3136), 256, 0, stream>>>(Qbuf, Kbuf, VTt, tw, Oat);

  // out = Oat @ Wo^T + bo  (fp32 out)
  gemm2_kernel<1><<<dim3(4, 392), 256, 0, stream>>>(Oat, wo_bf, bo, d_out);
}

// Round 13
// 353.381 us; speedup vs baseline: 1.1005x; 1.1005x over previous
//
#include <hip/hip_runtime.h>
#include <stdint.h>

typedef unsigned short u16;
typedef unsigned int   u32;
typedef __attribute__((ext_vector_type(8))) __bf16 bf16x8;
typedef __attribute__((ext_vector_type(4))) float  f32x4;
typedef __attribute__((ext_vector_type(4))) short  s16x4;

#define NB  64
#define NQ  784
#define NK  196
#define NKP 208      // nk padded to 13*16
#define DM  512

static __device__ inline u16 f2bf(float f) {
  u32 u = __float_as_uint(f);
  u32 r = (u + 0x7fffu + ((u >> 16) & 1u)) >> 16;
  return (u16)r;
}

static __device__ inline bf16x8 ld8(const u16* p) {
  return *reinterpret_cast<const bf16x8*>(p);
}
static __device__ inline f32x4 mfma16(bf16x8 a, bf16x8 b, f32x4 c) {
  return __builtin_amdgcn_mfma_f32_16x16x32_bf16(a, b, c, 0, 0, 0);
}
// K=16 bf16 MFMA (4 bf16 per lane per operand)
static __device__ inline f32x4 mfma16k16(s16x4 a, s16x4 b, f32x4 c) {
#if __has_builtin(__builtin_amdgcn_mfma_f32_16x16x16bf16_1k)
  return __builtin_amdgcn_mfma_f32_16x16x16bf16_1k(a, b, c, 0, 0, 0);
#elif __has_builtin(__builtin_amdgcn_mfma_f32_16x16x16_bf16)
  typedef __attribute__((ext_vector_type(4))) __bf16 bf16x4_t;
  union { s16x4 s; bf16x4_t b; } ua, ub;
  ua.s = a; ub.s = b;
  return __builtin_amdgcn_mfma_f32_16x16x16_bf16(ua.b, ub.b, c, 0, 0, 0);
#else
  asm volatile("v_mfma_f32_16x16x16_bf16 %0, %1, %2, %0\n\ts_nop 7\n\ts_nop 7"
               : "+v"(c) : "v"(a), "v"(b));
  return c;
#endif
}

// wave-uniform float -> SGPR
static __device__ inline float sgpr_f(float x) {
  return __uint_as_float(__builtin_amdgcn_readfirstlane(__float_as_uint(x)));
}

// async global -> LDS, 16B per lane; LDS dest must be wave-uniform base
static __device__ inline void gl_lds16(const void* g, void* l) {
  __builtin_amdgcn_global_load_lds(
      (const __attribute__((address_space(1))) void*)g,
      (__attribute__((address_space(3))) void*)l, 16, 0, 0);
}

// ---------------- fp32 -> bf16 conversion ----------------
__global__ __launch_bounds__(256) void cvt_kernel(const float* __restrict__ in,
                                                  u16* __restrict__ out, int n) {
  int i = (blockIdx.x * 256 + threadIdx.x) * 4;
  if (i + 3 < n) {
    float4 f = *reinterpret_cast<const float4*>(in + i);
    ushort4 o;
    o.x = f2bf(f.x); o.y = f2bf(f.y); o.z = f2bf(f.z); o.w = f2bf(f.w);
    *reinterpret_cast<ushort4*>(out + i) = o;
  }
}

// ---------------- spatial-reduce + LayerNorm -> bf16 x_ln [64][208][512] ----------------
__global__ __launch_bounds__(256) void ln_kernel(const float* __restrict__ q,
                                                 const float* __restrict__ sr_w,
                                                 const float* __restrict__ sr_b,
                                                 const float* __restrict__ ln_w,
                                                 const float* __restrict__ ln_b,
                                                 u16* __restrict__ xln) {
  int wave = blockIdx.x * 4 + (threadIdx.x >> 6);
  int lane = threadIdx.x & 63;
  if (wave >= NB * NKP) return;
  int b = wave / NKP, n = wave % NKP;
  u16* outp = xln + ((size_t)(b * NKP + n)) * DM;
  if (n >= NK) {  // zero pad row
    *reinterpret_cast<uint4*>(outp + lane * 8) = make_uint4(0u, 0u, 0u, 0u);
    return;
  }
  int src_n = (2 * (n / 14)) * 28 + 2 * (n % 14);
  const float* row = q + ((size_t)(b * NQ + src_n)) * DM;
  int c0 = lane * 4, c1 = 256 + lane * 4;
  float4 x0 = *reinterpret_cast<const float4*>(row + c0);
  float4 x1 = *reinterpret_cast<const float4*>(row + c1);
  float4 w0 = *reinterpret_cast<const float4*>(sr_w + c0);
  float4 w1 = *reinterpret_cast<const float4*>(sr_w + c1);
  float4 s0 = *reinterpret_cast<const float4*>(sr_b + c0);
  float4 s1 = *reinterpret_cast<const float4*>(sr_b + c1);
  float y[8];
  y[0] = x0.x * w0.x + s0.x; y[1] = x0.y * w0.y + s0.y;
  y[2] = x0.z * w0.z + s0.z; y[3] = x0.w * w0.w + s0.w;
  y[4] = x1.x * w1.x + s1.x; y[5] = x1.y * w1.y + s1.y;
  y[6] = x1.z * w1.z + s1.z; y[7] = x1.w * w1.w + s1.w;
  float s = 0.f, ss = 0.f;
  #pragma unroll
  for (int i = 0; i < 8; i++) { s += y[i]; ss += y[i] * y[i]; }
  #pragma unroll
  for (int off = 1; off < 64; off <<= 1) {
    s += __shfl_xor(s, off); ss += __shfl_xor(ss, off);
  }
  float mu = s * (1.f / 512.f);
  float var = ss * (1.f / 512.f) - mu * mu;
  float rs = rsqrtf(var + 1e-5f);
  float4 lw0 = *reinterpret_cast<const float4*>(ln_w + c0);
  float4 lw1 = *reinterpret_cast<const float4*>(ln_w + c1);
  float4 lb0 = *reinterpret_cast<const float4*>(ln_b + c0);
  float4 lb1 = *reinterpret_cast<const float4*>(ln_b + c1);
  ushort4 o0, o1;
  o0.x = f2bf((y[0] - mu) * rs * lw0.x + lb0.x);
  o0.y = f2bf((y[1] - mu) * rs * lw0.y + lb0.y);
  o0.z = f2bf((y[2] - mu) * rs * lw0.z + lb0.z);
  o0.w = f2bf((y[3] - mu) * rs * lw0.w + lb0.w);
  o1.x = f2bf((y[4] - mu) * rs * lw1.x + lb1.x);
  o1.y = f2bf((y[5] - mu) * rs * lw1.y + lb1.y);
  o1.z = f2bf((y[6] - mu) * rs * lw1.z + lb1.z);
  o1.w = f2bf((y[7] - mu) * rs * lw1.w + lb1.w);
  *reinterpret_cast<ushort4*>(outp + c0) = o0;
  *reinterpret_cast<ushort4*>(outp + c1) = o1;
}

// ---------------- shared GEMM body: C[M,512] = A[M,512]*W[512,512]^T + bias ------------
// 128x128 tile, 4 waves (2x2) of 64x64, BK=32, global_load_lds staging, dbuf.
// OMODE: 0 = bf16 C [row][col], 1 = fp32 C [row][col],
//        2 = bf16 V tiled: C[b][kt][col(d)][k%16]
template <int OMODE>
static __device__ __forceinline__ void gemm_body(const u16* __restrict__ A,
                                                 const u16* __restrict__ Bw,
                                                 const float* __restrict__ bias,
                                                 void* __restrict__ Cptr,
                                                 int nt, int mt,
                                                 u16* Al0, u16* Al1,
                                                 u16* Bl0, u16* Bl1) {
  int wv = threadIdx.x >> 6, lane = threadIdx.x & 63;
  int lr = lane & 15, lg = lane >> 4;
  int wr = wv >> 1, wc = wv & 1;
  int row0 = mt * 128, col0 = nt * 128;

  auto stage = [&](int kk, int bi) {
    u16* Al = bi ? Al1 : Al0;
    u16* Bl = bi ? Bl1 : Bl0;
    #pragma unroll
    for (int i = 0; i < 4; i++) {
      int t = wv * 4 + i;                    // 0..15
      int rr = (t & 7) * 16 + (lane >> 2);
      int cc = lane & 3;
      if (t < 8) {
        gl_lds16(A + (size_t)(row0 + rr) * DM + kk + cc * 8, (char*)Al + t * 1024);
      } else {
        gl_lds16(Bw + (size_t)(col0 + rr) * DM + kk + cc * 8, (char*)Bl + (t - 8) * 1024);
      }
    }
  };

  f32x4 acc[4][4] = {};
  stage(0, 0);
  __syncthreads();
  for (int s = 0; s < 16; s++) {
    int bi = s & 1;
    if (s < 15) stage((s + 1) * 32, bi ^ 1);
    u16* Al = bi ? Al1 : Al0;
    u16* Bl = bi ? Bl1 : Bl0;
    bf16x8 am[4], bn[4];
    #pragma unroll
    for (int m = 0; m < 4; m++)
      am[m] = ld8(Al + (wr * 64 + m * 16 + lr) * 32 + lg * 8);
    #pragma unroll
    for (int n = 0; n < 4; n++)
      bn[n] = ld8(Bl + (wc * 64 + n * 16 + lr) * 32 + lg * 8);
    #pragma unroll
    for (int m = 0; m < 4; m++)
      #pragma unroll
      for (int n = 0; n < 4; n++)
        acc[m][n] = mfma16(am[m], bn[n], acc[m][n]);
    __syncthreads();
  }
  if (OMODE == 2) {
    #pragma unroll
    for (int n = 0; n < 4; n++) {
      int col = col0 + wc * 64 + n * 16 + lr;
      float bs = bias[col];
      #pragma unroll
      for (int m = 0; m < 4; m++) {
        int rbase = row0 + wr * 64 + m * 16 + lg * 4;
        int bb = rbase / NKP;
        int kr = rbase % NKP;          // kr&15 == lg*4
        ushort4 o4;
        o4.x = f2bf(acc[m][n][0] + bs);
        o4.y = f2bf(acc[m][n][1] + bs);
        o4.z = f2bf(acc[m][n][2] + bs);
        o4.w = f2bf(acc[m][n][3] + bs);
        size_t dst = (((size_t)bb * 13 + (kr >> 4)) * 512 + col) * 16 + (kr & 15);
        *reinterpret_cast<ushort4*>(&((u16*)Cptr)[dst]) = o4;
      }
    }
  } else {
    #pragma unroll
    for (int n = 0; n < 4; n++) {
      int col = col0 + wc * 64 + n * 16 + lr;
      float bs = bias[col];
      #pragma unroll
      for (int m = 0; m < 4; m++) {
        #pragma unroll
        for (int r = 0; r < 4; r++) {
          int row = row0 + wr * 64 + m * 16 + lg * 4 + r;
          float v = acc[m][n][r] + bs;
          if (OMODE == 0) {
            ((u16*)Cptr)[(size_t)row * DM + col] = f2bf(v);
          } else {
            ((float*)Cptr)[(size_t)row * DM + col] = v;
          }
        }
      }
    }
  }
}

template <int OMODE>
__global__ __launch_bounds__(256) void gemm2_kernel(const u16* __restrict__ A,
                                                    const u16* __restrict__ Bw,
                                                    const float* __restrict__ bias,
                                                    void* __restrict__ Cptr) {
  __shared__ __align__(16) u16 Al[2][128 * 32];
  __shared__ __align__(16) u16 Bl[2][128 * 32];
  gemm_body<OMODE>(A, Bw, bias, Cptr, blockIdx.x, blockIdx.y,
                   &Al[0][0], &Al[1][0], &Bl[0][0], &Bl[1][0]);
}

// fused K-proj (OMODE 0) + V-proj (OMODE 2): blockIdx.z selects.
__global__ __launch_bounds__(256) void kvgemm_kernel(const u16* __restrict__ A,
                                                     const u16* __restrict__ Wk,
                                                     const float* __restrict__ bk,
                                                     void* __restrict__ Kout,
                                                     const u16* __restrict__ Wv,
                                                     const float* __restrict__ bv,
                                                     void* __restrict__ Vout) {
  __shared__ __align__(16) u16 Al[2][128 * 32];
  __shared__ __align__(16) u16 Bl[2][128 * 32];
  if (blockIdx.z == 0) {
    gemm_body<0>(A, Wk, bk, Kout, blockIdx.x, blockIdx.y,
                 &Al[0][0], &Al[1][0], &Bl[0][0], &Bl[1][0]);
  } else {
    gemm_body<2>(A, Wv, bv, Vout, blockIdx.x, blockIdx.y,
                 &Al[0][0], &Al[1][0], &Bl[0][0], &Bl[1][0]);
  }
}

// ---------------- fused attn: round-11 base + early-V software pipeline ----------------
// grid 3136 XCD-clustered (id%8 == b%8). Chunk-major Q (staged once) + K
// (double-buffered) in LDS, imm-offset ds_reads, zero per-load VALU.
// Round-13 change: the 8 independent V fragment loads are issued at PHASE
// START (right after the async stageK issue), so their ~300cyc L2 latency
// overlaps the whole QK^T h-loop + softmax instead of serializing before PV.
// Affordable now because Q-in-LDS freed 64 VGPR (round-11 VGPR=100; +vb=16).
__global__ __launch_bounds__(256) void attn_kernel(const u16* __restrict__ Q,
                                                   const u16* __restrict__ K,
                                                   const u16* __restrict__ VTt,
                                                   const float* __restrict__ tw,
                                                   u16* __restrict__ Oat) {
  __shared__ __align__(16) u16 Ql[16 * 512];      // 16KB, chunk-major
  __shared__ __align__(16) u16 Kl[2][16 * 512];   // 2 x 16KB, chunk-major
  int i = blockIdx.x;
  int g8 = i & 7;            // XCD group == b%8
  int j = i >> 3;            // 0..391
  int qt = j % 49;
  int b = g8 + 8 * (j / 49);
  int tid = threadIdx.x, wv = tid >> 6, lane = tid & 63;
  int lr = lane & 15, lg = lane >> 4;
  int q0 = qt * 16, g0 = wv * 2;

  const u16* Qb = Q + ((size_t)(b * NQ + q0)) * DM;
  const u16* Kb = K + (size_t)b * NKP * DM;
  const u16* Vtb = VTt + (size_t)b * 13 * 8192;

  // wave-uniform mixing weights -> SGPRs (1/sqrt(64) folded)
  float w0[8], w1[8];
  #pragma unroll
  for (int h = 0; h < 8; h++) {
    w0[h] = sgpr_f(tw[(g0 + 0) * 8 + h] * 0.125f);
    w1[h] = sgpr_f(tw[(g0 + 1) * 8 + h] * 0.125f);
  }

  // chunk-major staging: slot s = g*64+lane -> (c = g*4 + lane>>4, r = lane&15)
  auto stageK = [&](int kt, int bi) {
    #pragma unroll
    for (int i2 = 0; i2 < 4; i2++) {
      int g = wv * 4 + i2;
      gl_lds16(Kb + (size_t)(kt * 16 + (lane & 15)) * DM + (g * 4 + (lane >> 4)) * 8,
               (char*)&Kl[bi][0] + g * 1024);
    }
  };
  #pragma unroll
  for (int i2 = 0; i2 < 4; i2++) {
    int g = wv * 4 + i2;
    gl_lds16(Qb + (size_t)(lane & 15) * DM + (g * 4 + (lane >> 4)) * 8,
             (char*)Ql + g * 1024);
  }
  stageK(0, 0);
  __syncthreads();

  // fixed per-lane fragment base (u16 elems): byte lg*256 + lr*16
  const u16* qbase = Ql + lg * 128 + lr * 8;

  f32x4 o[2][4] = {};
  float sum0 = 0.f, sum1 = 0.f;

  for (int kt = 0; kt < 13; kt++) {
    int bi = kt & 1;
    if (kt < 12) stageK(kt + 1, bi ^ 1);

    // EARLY V: issue all 8 independent fragment loads now; consumed in PV
    // after softmax -> latency hidden under QK^T + exp.
    s16x4 vb[2][4];
    #pragma unroll
    for (int gi = 0; gi < 2; gi++) {
      #pragma unroll
      for (int j2 = 0; j2 < 4; j2++) {
        int d = (g0 + gi) * 64 + j2 * 16 + lr;
        vb[gi][j2] = *reinterpret_cast<const s16x4*>(
            Vtb + (size_t)kt * 8192 + d * 16 + lg * 4);
      }
    }

    const u16* kbase = &Kl[bi][0] + lg * 128 + lr * 8;

    // QK^T (swapped): lane holds q = lr, k = kt*16 + lg*4 + r.
    // All ds_reads: base + compile-time imm. t4 independent per h.
    f32x4 sa = {0.f, 0.f, 0.f, 0.f};
    f32x4 sb = {0.f, 0.f, 0.f, 0.f};
    #pragma unroll
    for (int h = 0; h < 8; h++) {
      bf16x8 kf0 = ld8(kbase + h * 1024);
      bf16x8 kf1 = ld8(kbase + h * 1024 + 512);
      bf16x8 qf0 = ld8(qbase + h * 1024);
      bf16x8 qf1 = ld8(qbase + h * 1024 + 512);
      f32x4 t4 = {0.f, 0.f, 0.f, 0.f};
      t4 = mfma16(kf0, qf0, t4);
      t4 = mfma16(kf1, qf1, t4);
      sa += t4 * w0[h];
      sb += t4 * w1[h];
    }
    bool masked = (kt == 12) && (lg != 0);   // k >= 196
    float a0 = masked ? 0.f : __expf(sa[0]);
    float a1 = masked ? 0.f : __expf(sa[1]);
    float a2 = masked ? 0.f : __expf(sa[2]);
    float a3 = masked ? 0.f : __expf(sa[3]);
    float b0 = masked ? 0.f : __expf(sb[0]);
    float b1 = masked ? 0.f : __expf(sb[1]);
    float b2 = masked ? 0.f : __expf(sb[2]);
    float b3 = masked ? 0.f : __expf(sb[3]);
    sum0 += (a0 + a1) + (a2 + a3);
    sum1 += (b0 + b1) + (b2 + b3);
    union { __bf16 e[4]; s16x4 sv; } pk;
    pk.e[0] = (__bf16)a0; pk.e[1] = (__bf16)a1;
    pk.e[2] = (__bf16)a2; pk.e[3] = (__bf16)a3;
    s16x4 pa0 = pk.sv;
    pk.e[0] = (__bf16)b0; pk.e[1] = (__bf16)b1;
    pk.e[2] = (__bf16)b2; pk.e[3] = (__bf16)b3;
    s16x4 pa1 = pk.sv;

    // PV: o += P[kt] x V[kt]  (vb loaded at phase start)
    #pragma unroll
    for (int gi = 0; gi < 2; gi++) {
      s16x4 pa = (gi == 0) ? pa0 : pa1;
      #pragma unroll
      for (int j2 = 0; j2 < 4; j2++)
        o[gi][j2] = mfma16k16(pa, vb[gi][j2], o[gi][j2]);
    }
    __syncthreads();   // stage(kt+1) complete; all waves done with Kl[bi]
  }

  // complete row sums (k split across lane groups 16 apart)
  sum0 += __shfl_xor(sum0, 16); sum0 += __shfl_xor(sum0, 32);
  sum1 += __shfl_xor(sum1, 16); sum1 += __shfl_xor(sum1, 32);
  float inv0 = 1.0f / sum0;    // valid for q = lr
  float inv1 = 1.0f / sum1;
  float iv0[4], iv1[4];
  #pragma unroll
  for (int r = 0; r < 4; r++) {
    iv0[r] = __shfl(inv0, lg * 4 + r);
    iv1[r] = __shfl(inv1, lg * 4 + r);
  }
  #pragma unroll
  for (int gi = 0; gi < 2; gi++) {
    int g = g0 + gi;
    #pragma unroll
    for (int j2 = 0; j2 < 4; j2++) {
      #pragma unroll
      for (int r = 0; r < 4; r++) {
        int q = lg * 4 + r;
        float iv = (gi == 0) ? iv0[r] : iv1[r];
        Oat[((size_t)(b * NQ + q0 + q)) * DM + g * 64 + j2 * 16 + lr] =
            f2bf(o[gi][j2][r] * iv);
      }
    }
  }
}

// ---------------- launch ----------------
extern "C" void kernel_launch(void* const* d_in, const int* in_sizes, int n_in,
                              void* d_out, int out_size, void* d_ws, size_t ws_size,
                              hipStream_t stream) {
  const float* queries = (const float*)d_in[0];
  const float* Wq = (const float*)d_in[3];
  const float* bq = (const float*)d_in[4];
  const float* Wk = (const float*)d_in[5];
  const float* bk = (const float*)d_in[6];
  const float* Wv = (const float*)d_in[7];
  const float* bv = (const float*)d_in[8];
  const float* Wo = (const float*)d_in[9];
  const float* bo = (const float*)d_in[10];
  const float* sr_w = (const float*)d_in[11];
  const float* sr_b = (const float*)d_in[12];
  const float* ln_w = (const float*)d_in[13];
  const float* ln_b = (const float*)d_in[14];
  const float* tw = (const float*)d_in[15];

  char* ws = (char*)d_ws;
  u16* wq_bf = (u16*)(ws + 0);          // 512KB
  u16* wk_bf = (u16*)(ws + 524288);
  u16* wv_bf = (u16*)(ws + 1048576);
  u16* wo_bf = (u16*)(ws + 1572864);
  u16* xln   = (u16*)(ws + 2097152);    // 64*208*512*2 = 13,631,488
  u16* Kbuf  = (u16*)(ws + 15728640);   // 13,631,488
  u16* VTt   = (u16*)(ws + 29360128);   // 64*13*512*16*2 = 13,631,488
  u16* Qbuf  = (u16*)(ws + 42991616);   // 64*784*512*2 = 51,380,224
  u16* qbf   = (u16*)(ws + 94371840);   // 51,380,224 -> end 145,752,064
  u16* Oat   = qbf;                     // qbf dead after Q-proj; attn reuses it
  if (ws_size < 145752064u) return;     // fail loudly (output stays poisoned)

  const int NW = 262144;  // 512*512
  cvt_kernel<<<256, 256, 0, stream>>>(Wq, wq_bf, NW);
  cvt_kernel<<<256, 256, 0, stream>>>(Wk, wk_bf, NW);
  cvt_kernel<<<256, 256, 0, stream>>>(Wv, wv_bf, NW);
  cvt_kernel<<<256, 256, 0, stream>>>(Wo, wo_bf, NW);
  // queries fp32 -> bf16 (25,690,112 elements)
  cvt_kernel<<<25088, 256, 0, stream>>>(queries, qbf, NB * NQ * DM);

  ln_kernel<<<(NB * NKP) / 4, 256, 0, stream>>>(queries, sr_w, sr_b, ln_w, ln_b, xln);

  // Q = qbf @ Wq^T + bq   M = 50176
  gemm2_kernel<0><<<dim3(4, 392), 256, 0, stream>>>(qbf, wq_bf, bq, Qbuf);
  // K-proj + V-proj fused (z=0: K [row][col] bf16; z=1: V tiled)
  kvgemm_kernel<<<dim3(4, 104, 2), 256, 0, stream>>>(xln, wk_bf, bk, Kbuf,
                                                     wv_bf, bv, VTt);

  attn_kernel<<<dim3(3136), 256, 0, stream>>>(Qbuf, Kbuf, VTt, tw, Oat);

  // out = Oat @ Wo^T + bo  (fp32 out)
  gemm2_kernel<1><<<dim3(4, 392), 256, 0, stream>>>(Oat, wo_bf, bo, d_out);
}

// Round 14
// 301.885 us; speedup vs baseline: 1.2882x; 1.1706x over previous
//
#include <hip/hip_runtime.h>
#include <stdint.h>

typedef unsigned short u16;
typedef unsigned int   u32;
typedef __attribute__((ext_vector_type(8))) __bf16 bf16x8;
typedef __attribute__((ext_vector_type(4))) float  f32x4;
typedef __attribute__((ext_vector_type(4))) short  s16x4;

#define NB  64
#define NQ  784
#define NK  196
#define NKP 208      // nk padded to 13*16
#define DM  512

static __device__ inline u16 f2bf(float f) {
  u32 u = __float_as_uint(f);
  u32 r = (u + 0x7fffu + ((u >> 16) & 1u)) >> 16;
  return (u16)r;
}

static __device__ inline bf16x8 ld8(const u16* p) {
  return *reinterpret_cast<const bf16x8*>(p);
}
static __device__ inline f32x4 mfma16(bf16x8 a, bf16x8 b, f32x4 c) {
  return __builtin_amdgcn_mfma_f32_16x16x32_bf16(a, b, c, 0, 0, 0);
}
// K=16 bf16 MFMA (4 bf16 per lane per operand)
static __device__ inline f32x4 mfma16k16(s16x4 a, s16x4 b, f32x4 c) {
#if __has_builtin(__builtin_amdgcn_mfma_f32_16x16x16bf16_1k)
  return __builtin_amdgcn_mfma_f32_16x16x16bf16_1k(a, b, c, 0, 0, 0);
#elif __has_builtin(__builtin_amdgcn_mfma_f32_16x16x16_bf16)
  typedef __attribute__((ext_vector_type(4))) __bf16 bf16x4_t;
  union { s16x4 s; bf16x4_t b; } ua, ub;
  ua.s = a; ub.s = b;
  return __builtin_amdgcn_mfma_f32_16x16x16_bf16(ua.b, ub.b, c, 0, 0, 0);
#else
  asm volatile("v_mfma_f32_16x16x16_bf16 %0, %1, %2, %0\n\ts_nop 7\n\ts_nop 7"
               : "+v"(c) : "v"(a), "v"(b));
  return c;
#endif
}

// wave-uniform float -> SGPR
static __device__ inline float sgpr_f(float x) {
  return __uint_as_float(__builtin_amdgcn_readfirstlane(__float_as_uint(x)));
}

// async global -> LDS, 16B per lane; LDS dest must be wave-uniform base
static __device__ inline void gl_lds16(const void* g, void* l) {
  __builtin_amdgcn_global_load_lds(
      (const __attribute__((address_space(1))) void*)g,
      (__attribute__((address_space(3))) void*)l, 16, 0, 0);
}

// ---------------- fp32 -> bf16 conversion (weights) ----------------
__global__ __launch_bounds__(256) void cvt_kernel(const float* __restrict__ in,
                                                  u16* __restrict__ out, int n) {
  int i = (blockIdx.x * 256 + threadIdx.x) * 4;
  if (i + 3 < n) {
    float4 f = *reinterpret_cast<const float4*>(in + i);
    ushort4 o;
    o.x = f2bf(f.x); o.y = f2bf(f.y); o.z = f2bf(f.z); o.w = f2bf(f.w);
    *reinterpret_cast<ushort4*>(out + i) = o;
  }
}

// ---------------- fused queries cvt (fp32->bf16) + spatial-reduce LayerNorm ------------
// One wave per q-row: read queries row ONCE, write qbf row; if the row is a
// stride-2 subsample point also compute sr*x+b -> LN -> write xln row.
// Extra waves (w >= NB*NQ) zero the xln pad rows (n in [196,208)).
__global__ __launch_bounds__(256) void cvtln_kernel(const float* __restrict__ q,
                                                    const float* __restrict__ sr_w,
                                                    const float* __restrict__ sr_b,
                                                    const float* __restrict__ ln_w,
                                                    const float* __restrict__ ln_b,
                                                    u16* __restrict__ qbf,
                                                    u16* __restrict__ xln) {
  int w = blockIdx.x * 4 + (threadIdx.x >> 6);
  int lane = threadIdx.x & 63;
  if (w >= NB * NQ) {
    int w2 = w - NB * NQ;
    if (w2 < NB * 12) {
      int b = w2 / 12, pr = w2 % 12;
      u16* outp = xln + ((size_t)(b * NKP + NK + pr)) * DM;
      *reinterpret_cast<uint4*>(outp + lane * 8) = make_uint4(0u, 0u, 0u, 0u);
    }
    return;
  }
  int b = w / NQ, n = w % NQ;
  const float* row = q + ((size_t)w) * DM;
  int c0 = lane * 4, c1 = 256 + lane * 4;
  float4 x0 = *reinterpret_cast<const float4*>(row + c0);
  float4 x1 = *reinterpret_cast<const float4*>(row + c1);
  // write bf16 queries
  u16* qp = qbf + (size_t)w * DM;
  ushort4 q0, q1;
  q0.x = f2bf(x0.x); q0.y = f2bf(x0.y); q0.z = f2bf(x0.z); q0.w = f2bf(x0.w);
  q1.x = f2bf(x1.x); q1.y = f2bf(x1.y); q1.z = f2bf(x1.z); q1.w = f2bf(x1.w);
  *reinterpret_cast<ushort4*>(qp + c0) = q0;
  *reinterpret_cast<ushort4*>(qp + c1) = q1;
  // spatial-reduce + LN path
  int y = n / 28, x = n % 28;
  if ((y & 1) | (x & 1)) return;
  int np = (y >> 1) * 14 + (x >> 1);
  float4 w0 = *reinterpret_cast<const float4*>(sr_w + c0);
  float4 w1 = *reinterpret_cast<const float4*>(sr_w + c1);
  float4 s0 = *reinterpret_cast<const float4*>(sr_b + c0);
  float4 s1 = *reinterpret_cast<const float4*>(sr_b + c1);
  float yv[8];
  yv[0] = x0.x * w0.x + s0.x; yv[1] = x0.y * w0.y + s0.y;
  yv[2] = x0.z * w0.z + s0.z; yv[3] = x0.w * w0.w + s0.w;
  yv[4] = x1.x * w1.x + s1.x; yv[5] = x1.y * w1.y + s1.y;
  yv[6] = x1.z * w1.z + s1.z; yv[7] = x1.w * w1.w + s1.w;
  float s = 0.f, ss = 0.f;
  #pragma unroll
  for (int i = 0; i < 8; i++) { s += yv[i]; ss += yv[i] * yv[i]; }
  #pragma unroll
  for (int off = 1; off < 64; off <<= 1) {
    s += __shfl_xor(s, off); ss += __shfl_xor(ss, off);
  }
  float mu = s * (1.f / 512.f);
  float var = ss * (1.f / 512.f) - mu * mu;
  float rs = rsqrtf(var + 1e-5f);
  float4 lw0 = *reinterpret_cast<const float4*>(ln_w + c0);
  float4 lw1 = *reinterpret_cast<const float4*>(ln_w + c1);
  float4 lb0 = *reinterpret_cast<const float4*>(ln_b + c0);
  float4 lb1 = *reinterpret_cast<const float4*>(ln_b + c1);
  ushort4 o0, o1;
  o0.x = f2bf((yv[0] - mu) * rs * lw0.x + lb0.x);
  o0.y = f2bf((yv[1] - mu) * rs * lw0.y + lb0.y);
  o0.z = f2bf((yv[2] - mu) * rs * lw0.z + lb0.z);
  o0.w = f2bf((yv[3] - mu) * rs * lw0.w + lb0.w);
  o1.x = f2bf((yv[4] - mu) * rs * lw1.x + lb1.x);
  o1.y = f2bf((yv[5] - mu) * rs * lw1.y + lb1.y);
  o1.z = f2bf((yv[6] - mu) * rs * lw1.z + lb1.z);
  o1.w = f2bf((yv[7] - mu) * rs * lw1.w + lb1.w);
  u16* outp = xln + ((size_t)(b * NKP + np)) * DM;
  *reinterpret_cast<ushort4*>(outp + c0) = o0;
  *reinterpret_cast<ushort4*>(outp + c1) = o1;
}

// ---------------- shared GEMM body: C[M,512] = A[M,512]*W[512,512]^T + bias ------------
// 128x128 tile, 4 waves (2x2) of 64x64, BK=32, global_load_lds staging, dbuf.
// OMODE: 0 = bf16 C [row][col], 1 = fp32 C [row][col],
//        2 = bf16 V tiled: C[b][kt][col(d)][k%16]
template <int OMODE>
static __device__ __forceinline__ void gemm_body(const u16* __restrict__ A,
                                                 const u16* __restrict__ Bw,
                                                 const float* __restrict__ bias,
                                                 void* __restrict__ Cptr,
                                                 int nt, int mt,
                                                 u16* Al0, u16* Al1,
                                                 u16* Bl0, u16* Bl1) {
  int wv = threadIdx.x >> 6, lane = threadIdx.x & 63;
  int lr = lane & 15, lg = lane >> 4;
  int wr = wv >> 1, wc = wv & 1;
  int row0 = mt * 128, col0 = nt * 128;

  auto stage = [&](int kk, int bi) {
    u16* Al = bi ? Al1 : Al0;
    u16* Bl = bi ? Bl1 : Bl0;
    #pragma unroll
    for (int i = 0; i < 4; i++) {
      int t = wv * 4 + i;                    // 0..15
      int rr = (t & 7) * 16 + (lane >> 2);
      int cc = lane & 3;
      if (t < 8) {
        gl_lds16(A + (size_t)(row0 + rr) * DM + kk + cc * 8, (char*)Al + t * 1024);
      } else {
        gl_lds16(Bw + (size_t)(col0 + rr) * DM + kk + cc * 8, (char*)Bl + (t - 8) * 1024);
      }
    }
  };

  f32x4 acc[4][4] = {};
  stage(0, 0);
  __syncthreads();
  for (int s = 0; s < 16; s++) {
    int bi = s & 1;
    if (s < 15) stage((s + 1) * 32, bi ^ 1);
    u16* Al = bi ? Al1 : Al0;
    u16* Bl = bi ? Bl1 : Bl0;
    bf16x8 am[4], bn[4];
    #pragma unroll
    for (int m = 0; m < 4; m++)
      am[m] = ld8(Al + (wr * 64 + m * 16 + lr) * 32 + lg * 8);
    #pragma unroll
    for (int n = 0; n < 4; n++)
      bn[n] = ld8(Bl + (wc * 64 + n * 16 + lr) * 32 + lg * 8);
    #pragma unroll
    for (int m = 0; m < 4; m++)
      #pragma unroll
      for (int n = 0; n < 4; n++)
        acc[m][n] = mfma16(am[m], bn[n], acc[m][n]);
    __syncthreads();
  }
  if (OMODE == 2) {
    #pragma unroll
    for (int n = 0; n < 4; n++) {
      int col = col0 + wc * 64 + n * 16 + lr;
      float bs = bias[col];
      #pragma unroll
      for (int m = 0; m < 4; m++) {
        int rbase = row0 + wr * 64 + m * 16 + lg * 4;
        int bb = rbase / NKP;
        int kr = rbase % NKP;          // kr&15 == lg*4
        ushort4 o4;
        o4.x = f2bf(acc[m][n][0] + bs);
        o4.y = f2bf(acc[m][n][1] + bs);
        o4.z = f2bf(acc[m][n][2] + bs);
        o4.w = f2bf(acc[m][n][3] + bs);
        size_t dst = (((size_t)bb * 13 + (kr >> 4)) * 512 + col) * 16 + (kr & 15);
        *reinterpret_cast<ushort4*>(&((u16*)Cptr)[dst]) = o4;
      }
    }
  } else {
    #pragma unroll
    for (int n = 0; n < 4; n++) {
      int col = col0 + wc * 64 + n * 16 + lr;
      float bs = bias[col];
      #pragma unroll
      for (int m = 0; m < 4; m++) {
        #pragma unroll
        for (int r = 0; r < 4; r++) {
          int row = row0 + wr * 64 + m * 16 + lg * 4 + r;
          float v = acc[m][n][r] + bs;
          if (OMODE == 0) {
            ((u16*)Cptr)[(size_t)row * DM + col] = f2bf(v);
          } else {
            ((float*)Cptr)[(size_t)row * DM + col] = v;
          }
        }
      }
    }
  }
}

template <int OMODE>
__global__ __launch_bounds__(256) void gemm2_kernel(const u16* __restrict__ A,
                                                    const u16* __restrict__ Bw,
                                                    const float* __restrict__ bias,
                                                    void* __restrict__ Cptr) {
  __shared__ __align__(16) u16 Al[2][128 * 32];
  __shared__ __align__(16) u16 Bl[2][128 * 32];
  gemm_body<OMODE>(A, Bw, bias, Cptr, blockIdx.x, blockIdx.y,
                   &Al[0][0], &Al[1][0], &Bl[0][0], &Bl[1][0]);
}

// fused K-proj (OMODE 0) + V-proj (OMODE 2): blockIdx.z selects.
__global__ __launch_bounds__(256) void kvgemm_kernel(const u16* __restrict__ A,
                                                     const u16* __restrict__ Wk,
                                                     const float* __restrict__ bk,
                                                     void* __restrict__ Kout,
                                                     const u16* __restrict__ Wv,
                                                     const float* __restrict__ bv,
                                                     void* __restrict__ Vout) {
  __shared__ __align__(16) u16 Al[2][128 * 32];
  __shared__ __align__(16) u16 Bl[2][128 * 32];
  if (blockIdx.z == 0) {
    gemm_body<0>(A, Wk, bk, Kout, blockIdx.x, blockIdx.y,
                 &Al[0][0], &Al[1][0], &Bl[0][0], &Bl[1][0]);
  } else {
    gemm_body<2>(A, Wv, bv, Vout, blockIdx.x, blockIdx.y,
                 &Al[0][0], &Al[1][0], &Bl[0][0], &Bl[1][0]);
  }
}

// ---------------- fused attn: 32q per block (2 q-tiles), shared kf/vb ------------------
// grid 1600 XCD-clustered (id%8 == b%8), 4 waves; wave owns heads {2wv,2wv+1}
// for BOTH q-tiles. Per h: 2 kf reads SHARED by 4 MFMAs (2 per tile); PV vb
// loads shared by both tiles. K staged once per 32 q-rows. Chunk-major LDS,
// imm-offset reads; early-V; setprio around MFMA clusters (T5). qc==24 tail:
// tile B duplicates tile A, write-guarded.
__global__ __launch_bounds__(256) void attn_kernel(const u16* __restrict__ Q,
                                                   const u16* __restrict__ K,
                                                   const u16* __restrict__ VTt,
                                                   const float* __restrict__ tw,
                                                   u16* __restrict__ Oat) {
  __shared__ __align__(16) u16 Ql[2 * 16 * 512];  // 32KB, chunk-major, 2 tiles
  __shared__ __align__(16) u16 Kl[2][16 * 512];   // 2 x 16KB, chunk-major
  int i = blockIdx.x;
  int g8 = i & 7;            // XCD group == b%8
  int j = i >> 3;            // 0..199
  int qc = j % 25;
  int b = g8 + 8 * (j / 25);
  int tid = threadIdx.x, wv = tid >> 6, lane = tid & 63;
  int lr = lane & 15, lg = lane >> 4;
  int q0A = qc * 32;
  int q0B = (qc < 24) ? (q0A + 16) : q0A;   // tail duplicates tile A
  int g0 = wv * 2;

  const u16* Kb = K + (size_t)b * NKP * DM;
  const u16* Vtb = VTt + (size_t)b * 13 * 8192;

  // wave-uniform mixing weights -> SGPRs (1/sqrt(64) folded)
  float w0[8], w1[8];
  #pragma unroll
  for (int h = 0; h < 8; h++) {
    w0[h] = sgpr_f(tw[(g0 + 0) * 8 + h] * 0.125f);
    w1[h] = sgpr_f(tw[(g0 + 1) * 8 + h] * 0.125f);
  }

  // chunk-major staging: slot s = g*64+lane -> (c = g*4 + lane>>4, r = lane&15)
  auto stageK = [&](int kt, int bi) {
    #pragma unroll
    for (int i2 = 0; i2 < 4; i2++) {
      int g = wv * 4 + i2;
      gl_lds16(Kb + (size_t)(kt * 16 + (lane & 15)) * DM + (g * 4 + (lane >> 4)) * 8,
               (char*)&Kl[bi][0] + g * 1024);
    }
  };
  // stage both Q tiles (once)
  #pragma unroll
  for (int t = 0; t < 2; t++) {
    const u16* Qb = Q + ((size_t)b * NQ + (t ? q0B : q0A)) * DM;
    #pragma unroll
    for (int i2 = 0; i2 < 4; i2++) {
      int g = wv * 4 + i2;
      gl_lds16(Qb + (size_t)(lane & 15) * DM + (g * 4 + (lane >> 4)) * 8,
               (char*)Ql + t * 16384 + g * 1024);
    }
  }
  stageK(0, 0);
  __syncthreads();

  // fixed per-lane fragment bases (u16 elems)
  const u16* qbaseA = Ql + lg * 128 + lr * 8;
  const u16* qbaseB = Ql + 8192 + lg * 128 + lr * 8;

  f32x4 o[2][2][4] = {};      // [tile][g][j]
  float sumA0 = 0.f, sumA1 = 0.f, sumB0 = 0.f, sumB1 = 0.f;

  for (int kt = 0; kt < 13; kt++) {
    int bi = kt & 1;
    if (kt < 12) stageK(kt + 1, bi ^ 1);

    // EARLY V: 8 independent loads, shared by both tiles' PV
    s16x4 vb[2][4];
    #pragma unroll
    for (int gi = 0; gi < 2; gi++) {
      #pragma unroll
      for (int j2 = 0; j2 < 4; j2++) {
        int d = (g0 + gi) * 64 + j2 * 16 + lr;
        vb[gi][j2] = *reinterpret_cast<const s16x4*>(
            Vtb + (size_t)kt * 8192 + d * 16 + lg * 4);
      }
    }

    const u16* kbase = &Kl[bi][0] + lg * 128 + lr * 8;

    // QK^T (swapped) for both tiles; kf shared: per h 6 ds_reads + 4 MFMA.
    f32x4 saA = {0.f,0.f,0.f,0.f}, sbA = {0.f,0.f,0.f,0.f};
    f32x4 saB = {0.f,0.f,0.f,0.f}, sbB = {0.f,0.f,0.f,0.f};
    __builtin_amdgcn_s_setprio(1);
    #pragma unroll
    for (int h = 0; h < 8; h++) {
      bf16x8 kf0 = ld8(kbase + h * 1024);
      bf16x8 kf1 = ld8(kbase + h * 1024 + 512);
      bf16x8 qA0 = ld8(qbaseA + h * 1024);
      bf16x8 qA1 = ld8(qbaseA + h * 1024 + 512);
      bf16x8 qB0 = ld8(qbaseB + h * 1024);
      bf16x8 qB1 = ld8(qbaseB + h * 1024 + 512);
      f32x4 tA = {0.f,0.f,0.f,0.f};
      tA = mfma16(kf0, qA0, tA);
      tA = mfma16(kf1, qA1, tA);
      f32x4 tB = {0.f,0.f,0.f,0.f};
      tB = mfma16(kf0, qB0, tB);
      tB = mfma16(kf1, qB1, tB);
      saA += tA * w0[h]; sbA += tA * w1[h];
      saB += tB * w0[h]; sbB += tB * w1[h];
    }
    __builtin_amdgcn_s_setprio(0);

    bool masked = (kt == 12) && (lg != 0);   // k >= 196
    s16x4 pa[2][2];
    {
      float eA0 = masked ? 0.f : __expf(saA[0]);
      float eA1 = masked ? 0.f : __expf(saA[1]);
      float eA2 = masked ? 0.f : __expf(saA[2]);
      float eA3 = masked ? 0.f : __expf(saA[3]);
      float fA0 = masked ? 0.f : __expf(sbA[0]);
      float fA1 = masked ? 0.f : __expf(sbA[1]);
      float fA2 = masked ? 0.f : __expf(sbA[2]);
      float fA3 = masked ? 0.f : __expf(sbA[3]);
      sumA0 += (eA0 + eA1) + (eA2 + eA3);
      sumA1 += (fA0 + fA1) + (fA2 + fA3);
      union { __bf16 e[4]; s16x4 sv; } pk;
      pk.e[0] = (__bf16)eA0; pk.e[1] = (__bf16)eA1;
      pk.e[2] = (__bf16)eA2; pk.e[3] = (__bf16)eA3;
      pa[0][0] = pk.sv;
      pk.e[0] = (__bf16)fA0; pk.e[1] = (__bf16)fA1;
      pk.e[2] = (__bf16)fA2; pk.e[3] = (__bf16)fA3;
      pa[0][1] = pk.sv;
      float eB0 = masked ? 0.f : __expf(saB[0]);
      float eB1 = masked ? 0.f : __expf(saB[1]);
      float eB2 = masked ? 0.f : __expf(saB[2]);
      float eB3 = masked ? 0.f : __expf(saB[3]);
      float fB0 = masked ? 0.f : __expf(sbB[0]);
      float fB1 = masked ? 0.f : __expf(sbB[1]);
      float fB2 = masked ? 0.f : __expf(sbB[2]);
      float fB3 = masked ? 0.f : __expf(sbB[3]);
      sumB0 += (eB0 + eB1) + (eB2 + eB3);
      sumB1 += (fB0 + fB1) + (fB2 + fB3);
      pk.e[0] = (__bf16)eB0; pk.e[1] = (__bf16)eB1;
      pk.e[2] = (__bf16)eB2; pk.e[3] = (__bf16)eB3;
      pa[1][0] = pk.sv;
      pk.e[0] = (__bf16)fB0; pk.e[1] = (__bf16)fB1;
      pk.e[2] = (__bf16)fB2; pk.e[3] = (__bf16)fB3;
      pa[1][1] = pk.sv;
    }

    // PV: both tiles share vb
    __builtin_amdgcn_s_setprio(1);
    #pragma unroll
    for (int t = 0; t < 2; t++) {
      #pragma unroll
      for (int gi = 0; gi < 2; gi++) {
        #pragma unroll
        for (int j2 = 0; j2 < 4; j2++)
          o[t][gi][j2] = mfma16k16(pa[t][gi], vb[gi][j2], o[t][gi][j2]);
      }
    }
    __builtin_amdgcn_s_setprio(0);
    __syncthreads();   // stage(kt+1) complete; all waves done with Kl[bi]
  }

  // complete row sums (k split across lane groups 16 apart)
  sumA0 += __shfl_xor(sumA0, 16); sumA0 += __shfl_xor(sumA0, 32);
  sumA1 += __shfl_xor(sumA1, 16); sumA1 += __shfl_xor(sumA1, 32);
  sumB0 += __shfl_xor(sumB0, 16); sumB0 += __shfl_xor(sumB0, 32);
  sumB1 += __shfl_xor(sumB1, 16); sumB1 += __shfl_xor(sumB1, 32);
  float ivA0 = 1.0f / sumA0, ivA1 = 1.0f / sumA1;
  float ivB0 = 1.0f / sumB0, ivB1 = 1.0f / sumB1;
  #pragma unroll
  for (int t = 0; t < 2; t++) {
    if (t == 1 && qc == 24) break;   // tail: tile B is a duplicate
    int q0 = t ? q0B : q0A;
    #pragma unroll
    for (int gi = 0; gi < 2; gi++) {
      int g = g0 + gi;
      float ivsrc = t ? (gi ? ivB1 : ivB0) : (gi ? ivA1 : ivA0);
      #pragma unroll
      for (int r = 0; r < 4; r++) {
        int q = lg * 4 + r;
        float iv = __shfl(ivsrc, q);   // sum lives at lane lr == q
        #pragma unroll
        for (int j2 = 0; j2 < 4; j2++) {
          Oat[((size_t)(b * NQ + q0 + q)) * DM + g * 64 + j2 * 16 + lr] =
              f2bf(o[t][gi][j2][r] * iv);
        }
      }
    }
  }
}

// ---------------- launch ----------------
extern "C" void kernel_launch(void* const* d_in, const int* in_sizes, int n_in,
                              void* d_out, int out_size, void* d_ws, size_t ws_size,
                              hipStream_t stream) {
  const float* queries = (const float*)d_in[0];
  const float* Wq = (const float*)d_in[3];
  const float* bq = (const float*)d_in[4];
  const float* Wk = (const float*)d_in[5];
  const float* bk = (const float*)d_in[6];
  const float* Wv = (const float*)d_in[7];
  const float* bv = (const float*)d_in[8];
  const float* Wo = (const float*)d_in[9];
  const float* bo = (const float*)d_in[10];
  const float* sr_w = (const float*)d_in[11];
  const float* sr_b = (const float*)d_in[12];
  const float* ln_w = (const float*)d_in[13];
  const float* ln_b = (const float*)d_in[14];
  const float* tw = (const float*)d_in[15];

  char* ws = (char*)d_ws;
  u16* wq_bf = (u16*)(ws + 0);          // 512KB
  u16* wk_bf = (u16*)(ws + 524288);
  u16* wv_bf = (u16*)(ws + 1048576);
  u16* wo_bf = (u16*)(ws + 1572864);
  u16* xln   = (u16*)(ws + 2097152);    // 64*208*512*2 = 13,631,488
  u16* Kbuf  = (u16*)(ws + 15728640);   // 13,631,488
  u16* VTt   = (u16*)(ws + 29360128);   // 64*13*512*16*2 = 13,631,488
  u16* Qbuf  = (u16*)(ws + 42991616);   // 64*784*512*2 = 51,380,224
  u16* qbf   = (u16*)(ws + 94371840);   // 51,380,224 -> end 145,752,064
  u16* Oat   = qbf;                     // qbf dead after Q-proj; attn reuses it
  if (ws_size < 145752064u) return;     // fail loudly (output stays poisoned)

  const int NW = 262144;  // 512*512
  cvt_kernel<<<256, 256, 0, stream>>>(Wq, wq_bf, NW);
  cvt_kernel<<<256, 256, 0, stream>>>(Wk, wk_bf, NW);
  cvt_kernel<<<256, 256, 0, stream>>>(Wv, wv_bf, NW);
  cvt_kernel<<<256, 256, 0, stream>>>(Wo, wo_bf, NW);

  // fused queries cvt + LN: 64*784 + 64*12 waves
  cvtln_kernel<<<(NB * NQ + NB * 12 + 3) / 4, 256, 0, stream>>>(
      queries, sr_w, sr_b, ln_w, ln_b, qbf, xln);

  // Q = qbf @ Wq^T + bq   M = 50176
  gemm2_kernel<0><<<dim3(4, 392), 256, 0, stream>>>(qbf, wq_bf, bq, Qbuf);
  // K-proj + V-proj fused (z=0: K [row][col] bf16; z=1: V tiled)
  kvgemm_kernel<<<dim3(4, 104, 2), 256, 0, stream>>>(xln, wk_bf, bk, Kbuf,
                                                     wv_bf, bv, VTt);

  attn_kernel<<<dim3(1600), 256, 0, stream>>>(Qbuf, Kbuf, VTt, tw, Oat);

  // out = Oat @ Wo^T + bo  (fp32 out)
  gemm2_kernel<1><<<dim3(4, 392), 256, 0, stream>>>(Oat, wo_bf, bo, d_out);
}